// Round 4
// baseline (419.053 us; speedup 1.0000x reference)
//
#include <hip/hip_runtime.h>
#include <math.h>

#define T_LEN 4096
#define B_N 64
#define H_N 256
#define Q_N 1024
#define K_F 31
#define PAD 15
#define WL 1024

__device__ __forceinline__ float tanh_fast(float x) {
    // tanh(x) = 1 - 2/(exp(2x)+1); exact at +-inf saturation
    float e = __expf(2.0f * x);
    return 1.0f - 2.0f / (e + 1.0f);
}

// Per-batch arrival counters for the last-block-does-softmax pattern.
// Module device memory: NOT part of the harness workspace, so it is never
// re-poisoned. Zero at module load; the 8th arriver resets its slot to 0,
// so every graph replay sees 0 again. No block ever WAITS on the counter
// (7 of 8 just exit), so no deadlock is possible under any dispatch order.
__device__ int g_cnt[B_N];

// ---------------- K1: fused query-GEMV + conv + tanh + partial score,
// plus per-b softmax/argmax in the LAST of the 8 hc-blocks for that b.
// grid (8, B): block handles h-chunk hc (32 h) for batch b, all 1024 w.
__global__ __launch_bounds__(256) void k_score(
        const float* __restrict__ query, const float* __restrict__ wq,
        const float* __restrict__ bq, const float* __restrict__ conv_b,
        const float* __restrict__ ca, const int* __restrict__ mask,
        const float* __restrict__ init, const int* __restrict__ wstart,
        const float* __restrict__ conv_w, const float* __restrict__ ws_vec,
        const int* __restrict__ num_tokens,
        float* __restrict__ scoreP, float* __restrict__ alignW,
        float* __restrict__ out_ctx, float* __restrict__ out_nws) {
    int hc = blockIdx.x, b = blockIdx.y, tid = threadIdx.x;
    int h0 = hc * 32;
    __shared__ __align__(16) float qbuf[Q_N];
    __shared__ __align__(16) float loc[1056];
    __shared__ __align__(16) float cw[32][32];   // padded cols 31.. = 0
    __shared__ float qv[32], wv[32];
    __shared__ int isLast;
    __shared__ float red[8];    // softmax: [0..3] max, [4..7] sum
    __shared__ float redv[4];
    __shared__ int redi[4];
    int wsb = wstart[b];

    for (int i = tid; i < Q_N; i += 256) qbuf[i] = query[b * Q_N + i];
    for (int i = tid; i < 1056; i += 256) {
        float v = 0.f;
        if (i < 1054) {
            int p = wsb + i;
            if (p < PAD) v = init[b];
            else {
                int t = p - PAD;
                if (t < T_LEN && mask[b * T_LEN + t] != 0) v = ca[b * T_LEN + t];
            }
        }
        loc[i] = v;
    }
    for (int i = tid; i < 32 * 32; i += 256) {
        int r = i >> 5, c = i & 31;
        cw[r][c] = (c < K_F) ? conv_w[(h0 + r) * K_F + c] : 0.f;
    }
    if (tid < 32) wv[tid] = ws_vec[h0 + tid];
    __syncthreads();

    // q[h] = dot(query[b,:], wq[h0+h,:]) + bq + conv_b ; 8 threads per h-row
    {
        int h = tid >> 3, part = tid & 7;
        const float4* wrow = (const float4*)(wq + (size_t)(h0 + h) * Q_N) + part * 32;
        const float4* qrow = (const float4*)qbuf + part * 32;
        float acc = 0.f;
        #pragma unroll 8
        for (int i = 0; i < 32; i++) {
            float4 a = wrow[i], c = qrow[i];
            acc += a.x * c.x + a.y * c.y + a.z * c.z + a.w * c.w;
        }
        acc += __shfl_xor(acc, 1);
        acc += __shfl_xor(acc, 2);
        acc += __shfl_xor(acc, 4);
        if (part == 0) qv[h] = acc + bq[h0 + h] + conv_b[h0 + h];
    }
    __syncthreads();

    int w0 = tid * 4;                 // 4 consecutive w per thread
    // vectorized LDS read: 9 x float4 instead of 35 stride-4 scalar reads
    float4 lv4[9];
    #pragma unroll
    for (int j = 0; j < 9; j++) lv4[j] = *(const float4*)&loc[w0 + 4 * j];
    const float* l = (const float*)lv4;

    float s0 = 0.f, s1 = 0.f, s2 = 0.f, s3 = 0.f;
    for (int hh = 0; hh < 32; hh++) {
        float bias = qv[hh];
        float c0 = bias, c1 = bias, c2 = bias, c3 = bias;
        #pragma unroll
        for (int k = 0; k < 32; k += 4) {
            float4 cq = *(const float4*)&cw[hh][k];
            c0 += l[k + 0] * cq.x; c1 += l[k + 1] * cq.x; c2 += l[k + 2] * cq.x; c3 += l[k + 3] * cq.x;
            c0 += l[k + 1] * cq.y; c1 += l[k + 2] * cq.y; c2 += l[k + 3] * cq.y; c3 += l[k + 4] * cq.y;
            c0 += l[k + 2] * cq.z; c1 += l[k + 3] * cq.z; c2 += l[k + 4] * cq.z; c3 += l[k + 5] * cq.z;
            c0 += l[k + 3] * cq.w; c1 += l[k + 4] * cq.w; c2 += l[k + 5] * cq.w; c3 += l[k + 6] * cq.w;
        }
        float wh = wv[hh];
        s0 += wh * tanh_fast(c0); s1 += wh * tanh_fast(c1);
        s2 += wh * tanh_fast(c2); s3 += wh * tanh_fast(c3);
    }
    *(float4*)&scoreP[((size_t)hc * B_N + b) * WL + w0] = make_float4(s0, s1, s2, s3);

    // ---- arrival protocol: release own stores, count arrivals of this b ----
    __threadfence();                   // release: scoreP stores visible device-wide
    __syncthreads();                   // all threads of block fenced
    if (tid == 0) {
        int old = atomicAdd(&g_cnt[b], 1);
        isLast = (old == 7) ? 1 : 0;
        if (old == 7) atomicExch(&g_cnt[b], 0);  // self-reset for next iteration
    }
    __syncthreads();
    if (!isLast) return;
    __threadfence();                   // acquire: other blocks' scoreP now visible

    // ---- register-resident softmax + argmax + nws for batch b ----
    float s[4];
    #pragma unroll
    for (int k = 0; k < 4; k++) {
        int w = tid + 256 * k;
        float v = 0.f;
        #pragma unroll
        for (int p = 0; p < 8; p++) v += scoreP[((size_t)p * B_N + b) * WL + w];
        if (mask[b * T_LEN + wsb + w] == 0) v = -3.0e38f;
        s[k] = v;
    }
    float mx = fmaxf(fmaxf(s[0], s[1]), fmaxf(s[2], s[3]));
    #pragma unroll
    for (int o = 32; o > 0; o >>= 1) mx = fmaxf(mx, __shfl_xor(mx, o));
    if ((tid & 63) == 0) red[tid >> 6] = mx;
    __syncthreads();
    mx = fmaxf(fmaxf(red[0], red[1]), fmaxf(red[2], red[3]));

    float lsum = 0.f;
    #pragma unroll
    for (int k = 0; k < 4; k++) { s[k] = __expf(s[k] - mx); lsum += s[k]; }
    #pragma unroll
    for (int o = 32; o > 0; o >>= 1) lsum += __shfl_xor(lsum, o);
    if ((tid & 63) == 0) red[4 + (tid >> 6)] = lsum;
    __syncthreads();
    float inv = 1.0f / (red[4] + red[5] + red[6] + red[7]);

    float bv = -1.f; int bi = 0;
    #pragma unroll
    for (int k = 0; k < 4; k++) {       // ascending w within thread: strict > keeps first tie
        float a = s[k] * inv;
        alignW[b * WL + tid + 256 * k] = a;
        if (a > bv) { bv = a; bi = tid + 256 * k; }
    }
    #pragma unroll
    for (int o = 32; o > 0; o >>= 1) {
        float ov = __shfl_xor(bv, o); int oi = __shfl_xor(bi, o);
        if (ov > bv || (ov == bv && oi < bi)) { bv = ov; bi = oi; }
    }
    if ((tid & 63) == 0) { redv[tid >> 6] = bv; redi[tid >> 6] = bi; }
    __syncthreads();
    if (tid == 0) {
        float v = redv[0]; int i = redi[0];
        #pragma unroll
        for (int k = 1; k < 4; k++)
            if (redv[k] > v || (redv[k] == v && redi[k] < i)) { v = redv[k]; i = redi[k]; }
        int tstar = wsb + i;
        int nws = tstar - WL / 2;
        int lim = num_tokens[b] - WL;
        nws = nws < lim ? nws : lim;
        nws = nws > 0 ? nws : 0;
        out_nws[b] = (float)nws;
    }
    out_ctx[b * H_N + tid] = 0.f;   // 256 threads == H_N; K2 launches after K1 completes
}

// ---------------- K2: context (bx<16) + wide T-scatter (bx>=16)
// context: thread t: h-quad (t&63)*4, w-subgroup wj = t>>6 (4 subgroups x 16 rows)
// scatter: 4 blocks per b, one float4 group of T per thread
__global__ __launch_bounds__(256) void k_ctx_scatter(
        const float* __restrict__ tokens, const float* __restrict__ alignW,
        const int* __restrict__ mask, const float* __restrict__ ca,
        const int* __restrict__ wstart, float* __restrict__ out_ctx,
        float* __restrict__ out_align, float* __restrict__ out_cum) {
    int bx = blockIdx.x, b = blockIdx.y, tid = threadIdx.x;
    int wsb = wstart[b];
    __shared__ float av[64];
    __shared__ __align__(16) float4 red4[256];
    if (bx < 16) {
        if (tid < 64) av[tid] = alignW[b * WL + bx * 64 + tid];
        __syncthreads();
        int h4 = (tid & 63) * 4, wj = tid >> 6;
        const float* tokbase = tokens + ((size_t)(wsb + bx * 64 + wj) * B_N + b) * H_N + h4;
        float4 acc = make_float4(0.f, 0.f, 0.f, 0.f);
        #pragma unroll
        for (int j = 0; j < 16; j++) {      // fully unrolled: 16 independent loads in flight
            float a = av[wj + 4 * j];
            float4 t4 = *(const float4*)(tokbase + (size_t)(4 * j) * B_N * H_N);
            acc.x += a * t4.x; acc.y += a * t4.y; acc.z += a * t4.z; acc.w += a * t4.w;
        }
        red4[tid] = acc;
        __syncthreads();
        if (tid < 64) {
            float4 r0 = red4[tid], r1 = red4[tid + 64], r2 = red4[tid + 128], r3 = red4[tid + 192];
            float* dst = &out_ctx[b * H_N + tid * 4];
            atomicAdd(dst + 0, r0.x + r1.x + r2.x + r3.x);
            atomicAdd(dst + 1, r0.y + r1.y + r2.y + r3.y);
            atomicAdd(dst + 2, r0.z + r1.z + r2.z + r3.z);
            atomicAdd(dst + 3, r0.w + r1.w + r2.w + r3.w);
        }
    } else {
        int t4 = (bx - 16) * 256 + tid;     // float4 group index in [0, T/4)
        int4 m4 = ((const int4*)(mask + (size_t)b * T_LEN))[t4];
        float4 c4 = ((const float4*)(ca + (size_t)b * T_LEN))[t4];
        const float* aw = alignW + (size_t)b * WL;
        int j0 = t4 * 4 - wsb;
        float4 av4;
        av4.x = ((unsigned)(j0 + 0) < WL) ? aw[j0 + 0] : 0.f;
        av4.y = ((unsigned)(j0 + 1) < WL) ? aw[j0 + 1] : 0.f;
        av4.z = ((unsigned)(j0 + 2) < WL) ? aw[j0 + 2] : 0.f;
        av4.w = ((unsigned)(j0 + 3) < WL) ? aw[j0 + 3] : 0.f;
        float4 cum;
        cum.x = (m4.x != 0 ? c4.x : 0.f) + av4.x;
        cum.y = (m4.y != 0 ? c4.y : 0.f) + av4.y;
        cum.z = (m4.z != 0 ? c4.z : 0.f) + av4.z;
        cum.w = (m4.w != 0 ? c4.w : 0.f) + av4.w;
        ((float4*)(out_align + (size_t)b * T_LEN))[t4] = av4;
        ((float4*)(out_cum + (size_t)b * T_LEN))[t4] = cum;
    }
}

extern "C" void kernel_launch(void* const* d_in, const int* in_sizes, int n_in,
                              void* d_out, int out_size, void* d_ws, size_t ws_size,
                              hipStream_t stream) {
    const float* tokens     = (const float*)d_in[0];
    const int*   mask       = (const int*)  d_in[1];
    const int*   num_tokens = (const int*)  d_in[2];
    const float* query      = (const float*)d_in[3];   // (1,B,Q) -> base is query[0]
    const float* ca         = (const float*)d_in[4];
    const float* init       = (const float*)d_in[5];
    const int*   wstart     = (const int*)  d_in[6];
    const float* conv_w     = (const float*)d_in[7];
    const float* conv_b     = (const float*)d_in[8];
    const float* wq         = (const float*)d_in[9];
    const float* bq         = (const float*)d_in[10];
    const float* ws_vec     = (const float*)d_in[11];

    float* out       = (float*)d_out;
    float* out_ctx   = out;                          // B*H   = 16384
    float* out_cum   = out + 16384;                  // B*T   = 262144
    float* out_align = out + 16384 + 262144;         // B*T   = 262144
    float* out_nws   = out + 16384 + 2 * 262144;     // B     = 64 (as float)

    float* scoreP = (float*)d_ws;                    // 8*B*WL floats = 2MB
    float* alignW = scoreP + 8 * B_N * WL;           // B*WL

    k_score      <<<dim3(8, B_N),  dim3(256), 0, stream>>>(query, wq, bq, conv_b, ca, mask, init,
                                                           wstart, conv_w, ws_vec, num_tokens,
                                                           scoreP, alignW, out_ctx, out_nws);
    k_ctx_scatter<<<dim3(20, B_N), dim3(256), 0, stream>>>(tokens, alignW, mask, ca, wstart,
                                                           out_ctx, out_align, out_cum);
}

// Round 5
// 364.696 us; speedup vs baseline: 1.1490x; 1.1490x over previous
//
#include <hip/hip_runtime.h>
#include <math.h>

#define T_LEN 4096
#define B_N 64
#define H_N 256
#define Q_N 1024
#define K_F 31
#define PAD 15
#define WL 1024

__device__ __forceinline__ float tanh_fast(float x) {
    // tanh(x) = 1 - 2/(exp(2x)+1); exact at +-inf saturation
    float e = __expf(2.0f * x);
    return 1.0f - 2.0f / (e + 1.0f);
}

// ---------------- K1: fused query-GEMV + conv + tanh + partial score
// grid (8, B): block handles h-chunk hc (32 h) for batch b, all 1024 w.
// Also prefetches its 128-row slice of the token window (128 KB) through
// L2/L3 during the VALU-bound conv loop, so k_context hits Infinity Cache.
__global__ __launch_bounds__(256) void k_score(
        const float* __restrict__ tokens,
        const float* __restrict__ query, const float* __restrict__ wq,
        const float* __restrict__ bq, const float* __restrict__ conv_b,
        const float* __restrict__ ca, const int* __restrict__ mask,
        const float* __restrict__ init, const int* __restrict__ wstart,
        const float* __restrict__ conv_w, const float* __restrict__ ws_vec,
        float* __restrict__ scoreP) {
    int hc = blockIdx.x, b = blockIdx.y, tid = threadIdx.x;
    int h0 = hc * 32;
    __shared__ __align__(16) float qbuf[Q_N];
    __shared__ __align__(16) float loc[1056];
    __shared__ __align__(16) float cw[32][32];   // padded cols 31.. = 0
    __shared__ float qv[32], wv[32];
    int wsb = wstart[b];

    for (int i = tid; i < Q_N; i += 256) qbuf[i] = query[b * Q_N + i];
    for (int i = tid; i < 1056; i += 256) {
        float v = 0.f;
        if (i < 1054) {
            int p = wsb + i;
            if (p < PAD) v = init[b];
            else {
                int t = p - PAD;
                if (t < T_LEN && mask[b * T_LEN + t] != 0) v = ca[b * T_LEN + t];
            }
        }
        loc[i] = v;
    }
    for (int i = tid; i < 32 * 32; i += 256) {
        int r = i >> 5, c = i & 31;
        cw[r][c] = (c < K_F) ? conv_w[(h0 + r) * K_F + c] : 0.f;
    }
    if (tid < 32) wv[tid] = ws_vec[h0 + tid];
    __syncthreads();

    // q[h] = dot(query[b,:], wq[h0+h,:]) + bq + conv_b ; 8 threads per h-row
    {
        int h = tid >> 3, part = tid & 7;
        const float4* wrow = (const float4*)(wq + (size_t)(h0 + h) * Q_N) + part * 32;
        const float4* qrow = (const float4*)qbuf + part * 32;
        float acc = 0.f;
        #pragma unroll 8
        for (int i = 0; i < 32; i++) {
            float4 a = wrow[i], c = qrow[i];
            acc += a.x * c.x + a.y * c.y + a.z * c.z + a.w * c.w;
        }
        acc += __shfl_xor(acc, 1);
        acc += __shfl_xor(acc, 2);
        acc += __shfl_xor(acc, 4);
        if (part == 0) qv[h] = acc + bq[h0 + h] + conv_b[h0 + h];
    }
    __syncthreads();

    int w0 = tid * 4;                 // 4 consecutive w per thread
    // vectorized LDS read: 9 x float4 instead of 35 stride-4 scalar reads
    float4 lv4[9];
    #pragma unroll
    for (int j = 0; j < 9; j++) lv4[j] = *(const float4*)&loc[w0 + 4 * j];
    const float* l = (const float*)lv4;

    // token-window prefetch setup: this block's slice = w rows
    // [wsb + hc*128, +128), all 256 h -> 8192 float4, 32 per thread.
    // 4-deep pipeline: consume the load issued 4 hh-iterations ago
    // (~1080 cyc of conv FMAs > ~900 cyc HBM latency -> no stall).
    const float4* tok4 = (const float4*)(tokens + ((size_t)(wsb + hc * 128) * B_N + b) * H_N);
    float4 pf[4];
    #pragma unroll
    for (int u = 0; u < 4; u++) {
        int idx = u * 256 + tid;
        pf[u] = tok4[(size_t)(idx >> 6) * (B_N * H_N / 4) + (idx & 63)];
    }

    float s0 = 0.f, s1 = 0.f, s2 = 0.f, s3 = 0.f;
    for (int hg = 0; hg < 8; hg++) {
        #pragma unroll
        for (int u = 0; u < 4; u++) {
            int hh = hg * 4 + u;
            float bias = qv[hh];
            float c0 = bias, c1 = bias, c2 = bias, c3 = bias;
            #pragma unroll
            for (int k = 0; k < 32; k += 4) {
                float4 cq = *(const float4*)&cw[hh][k];
                c0 += l[k + 0] * cq.x; c1 += l[k + 1] * cq.x; c2 += l[k + 2] * cq.x; c3 += l[k + 3] * cq.x;
                c0 += l[k + 1] * cq.y; c1 += l[k + 2] * cq.y; c2 += l[k + 3] * cq.y; c3 += l[k + 4] * cq.y;
                c0 += l[k + 2] * cq.z; c1 += l[k + 3] * cq.z; c2 += l[k + 4] * cq.z; c3 += l[k + 5] * cq.z;
                c0 += l[k + 3] * cq.w; c1 += l[k + 4] * cq.w; c2 += l[k + 5] * cq.w; c3 += l[k + 6] * cq.w;
            }
            float wh = wv[hh];
            s0 += wh * tanh_fast(c0); s1 += wh * tanh_fast(c1);
            s2 += wh * tanh_fast(c2); s3 += wh * tanh_fast(c3);
            // consume prefetch issued 4 iterations ago (keeps load live, no DCE),
            // then reissue this slot for hh+4. u is compile-time -> static index.
            asm volatile("" :: "v"(pf[u].x), "v"(pf[u].y), "v"(pf[u].z), "v"(pf[u].w));
            if (hg < 7) {
                int idx = (hh + 4) * 256 + tid;
                pf[u] = tok4[(size_t)(idx >> 6) * (B_N * H_N / 4) + (idx & 63)];
            }
        }
    }
    *(float4*)&scoreP[((size_t)hc * B_N + b) * WL + w0] = make_float4(s0, s1, s2, s3);
}

// ---------------- K2: register-resident softmax + argmax + nws (no T scatter)
// grid (B): 256 threads, WL=1024 -> 4 scores per thread held in VGPRs.
__global__ __launch_bounds__(256) void k_softmax(
        const float* __restrict__ scoreP, const int* __restrict__ mask,
        const int* __restrict__ wstart, const int* __restrict__ num_tokens,
        float* __restrict__ alignW, float* __restrict__ out_ctx,
        float* __restrict__ out_nws) {
    int b = blockIdx.x, tid = threadIdx.x;
    __shared__ float red[8];    // [0..3] max, [4..7] sum
    __shared__ float redv[4];
    __shared__ int redi[4];
    int wsb = wstart[b];

    float s[4];
    #pragma unroll
    for (int k = 0; k < 4; k++) {
        int w = tid + 256 * k;
        float v = 0.f;
        #pragma unroll
        for (int p = 0; p < 8; p++) v += scoreP[((size_t)p * B_N + b) * WL + w];
        if (mask[b * T_LEN + wsb + w] == 0) v = -3.0e38f;
        s[k] = v;
    }
    // block max: wave shuffle reduce + 4-entry LDS combine
    float mx = fmaxf(fmaxf(s[0], s[1]), fmaxf(s[2], s[3]));
    #pragma unroll
    for (int o = 32; o > 0; o >>= 1) mx = fmaxf(mx, __shfl_xor(mx, o));
    if ((tid & 63) == 0) red[tid >> 6] = mx;
    __syncthreads();
    mx = fmaxf(fmaxf(red[0], red[1]), fmaxf(red[2], red[3]));

    // exp + block sum
    float lsum = 0.f;
    #pragma unroll
    for (int k = 0; k < 4; k++) { s[k] = __expf(s[k] - mx); lsum += s[k]; }
    #pragma unroll
    for (int o = 32; o > 0; o >>= 1) lsum += __shfl_xor(lsum, o);
    if ((tid & 63) == 0) red[4 + (tid >> 6)] = lsum;
    __syncthreads();
    float inv = 1.0f / (red[4] + red[5] + red[6] + red[7]);

    // normalize, write window alignment, argmax (first-max tie-break)
    float bv = -1.f; int bi = 0;
    #pragma unroll
    for (int k = 0; k < 4; k++) {       // ascending w within thread: strict > keeps first tie
        float a = s[k] * inv;
        alignW[b * WL + tid + 256 * k] = a;
        if (a > bv) { bv = a; bi = tid + 256 * k; }
    }
    #pragma unroll
    for (int o = 32; o > 0; o >>= 1) {
        float ov = __shfl_xor(bv, o); int oi = __shfl_xor(bi, o);
        if (ov > bv || (ov == bv && oi < bi)) { bv = ov; bi = oi; }
    }
    if ((tid & 63) == 0) { redv[tid >> 6] = bv; redi[tid >> 6] = bi; }
    __syncthreads();
    if (tid == 0) {
        float v = redv[0]; int i = redi[0];
        #pragma unroll
        for (int k = 1; k < 4; k++)
            if (redv[k] > v || (redv[k] == v && redi[k] < i)) { v = redv[k]; i = redi[k]; }
        int tstar = wsb + i;
        int nws = tstar - WL / 2;
        int lim = num_tokens[b] - WL;
        nws = nws < lim ? nws : lim;
        nws = nws > 0 ? nws : 0;
        out_nws[b] = (float)nws;
    }
    out_ctx[b * H_N + tid] = 0.f;   // 256 threads == H_N
}

// ---------------- K3: context (bx<16) + wide T-scatter (bx>=16)
// context: thread t: h-quad (t&63)*4, w-subgroup wj = t>>6 (4 subgroups x 16 rows)
// scatter: 4 blocks per b, one float4 group of T per thread
__global__ __launch_bounds__(256) void k_ctx_scatter(
        const float* __restrict__ tokens, const float* __restrict__ alignW,
        const int* __restrict__ mask, const float* __restrict__ ca,
        const int* __restrict__ wstart, float* __restrict__ out_ctx,
        float* __restrict__ out_align, float* __restrict__ out_cum) {
    int bx = blockIdx.x, b = blockIdx.y, tid = threadIdx.x;
    int wsb = wstart[b];
    __shared__ float av[64];
    __shared__ __align__(16) float4 red4[256];
    if (bx < 16) {
        if (tid < 64) av[tid] = alignW[b * WL + bx * 64 + tid];
        __syncthreads();
        int h4 = (tid & 63) * 4, wj = tid >> 6;
        const float* tokbase = tokens + ((size_t)(wsb + bx * 64 + wj) * B_N + b) * H_N + h4;
        float4 acc = make_float4(0.f, 0.f, 0.f, 0.f);
        #pragma unroll
        for (int j = 0; j < 16; j++) {      // fully unrolled: 16 independent loads in flight
            float a = av[wj + 4 * j];
            float4 t4 = *(const float4*)(tokbase + (size_t)(4 * j) * B_N * H_N);
            acc.x += a * t4.x; acc.y += a * t4.y; acc.z += a * t4.z; acc.w += a * t4.w;
        }
        red4[tid] = acc;
        __syncthreads();
        if (tid < 64) {
            float4 r0 = red4[tid], r1 = red4[tid + 64], r2 = red4[tid + 128], r3 = red4[tid + 192];
            float* dst = &out_ctx[b * H_N + tid * 4];
            atomicAdd(dst + 0, r0.x + r1.x + r2.x + r3.x);
            atomicAdd(dst + 1, r0.y + r1.y + r2.y + r3.y);
            atomicAdd(dst + 2, r0.z + r1.z + r2.z + r3.z);
            atomicAdd(dst + 3, r0.w + r1.w + r2.w + r3.w);
        }
    } else {
        int t4 = (bx - 16) * 256 + tid;     // float4 group index in [0, T/4)
        int4 m4 = ((const int4*)(mask + (size_t)b * T_LEN))[t4];
        float4 c4 = ((const float4*)(ca + (size_t)b * T_LEN))[t4];
        const float* aw = alignW + (size_t)b * WL;
        int j0 = t4 * 4 - wsb;
        float4 av4;
        av4.x = ((unsigned)(j0 + 0) < WL) ? aw[j0 + 0] : 0.f;
        av4.y = ((unsigned)(j0 + 1) < WL) ? aw[j0 + 1] : 0.f;
        av4.z = ((unsigned)(j0 + 2) < WL) ? aw[j0 + 2] : 0.f;
        av4.w = ((unsigned)(j0 + 3) < WL) ? aw[j0 + 3] : 0.f;
        float4 cum;
        cum.x = (m4.x != 0 ? c4.x : 0.f) + av4.x;
        cum.y = (m4.y != 0 ? c4.y : 0.f) + av4.y;
        cum.z = (m4.z != 0 ? c4.z : 0.f) + av4.z;
        cum.w = (m4.w != 0 ? c4.w : 0.f) + av4.w;
        ((float4*)(out_align + (size_t)b * T_LEN))[t4] = av4;
        ((float4*)(out_cum + (size_t)b * T_LEN))[t4] = cum;
    }
}

extern "C" void kernel_launch(void* const* d_in, const int* in_sizes, int n_in,
                              void* d_out, int out_size, void* d_ws, size_t ws_size,
                              hipStream_t stream) {
    const float* tokens     = (const float*)d_in[0];
    const int*   mask       = (const int*)  d_in[1];
    const int*   num_tokens = (const int*)  d_in[2];
    const float* query      = (const float*)d_in[3];   // (1,B,Q) -> base is query[0]
    const float* ca         = (const float*)d_in[4];
    const float* init       = (const float*)d_in[5];
    const int*   wstart     = (const int*)  d_in[6];
    const float* conv_w     = (const float*)d_in[7];
    const float* conv_b     = (const float*)d_in[8];
    const float* wq         = (const float*)d_in[9];
    const float* bq         = (const float*)d_in[10];
    const float* ws_vec     = (const float*)d_in[11];

    float* out       = (float*)d_out;
    float* out_ctx   = out;                          // B*H   = 16384
    float* out_cum   = out + 16384;                  // B*T   = 262144
    float* out_align = out + 16384 + 262144;         // B*T   = 262144
    float* out_nws   = out + 16384 + 2 * 262144;     // B     = 64 (as float)

    float* scoreP = (float*)d_ws;                    // 8*B*WL floats = 2MB
    float* alignW = scoreP + 8 * B_N * WL;           // B*WL

    k_score      <<<dim3(8, B_N),  dim3(256), 0, stream>>>(tokens, query, wq, bq, conv_b, ca, mask,
                                                           init, wstart, conv_w, ws_vec, scoreP);
    k_softmax    <<<dim3(B_N),     dim3(256), 0, stream>>>(scoreP, mask, wstart, num_tokens,
                                                           alignW, out_ctx, out_nws);
    k_ctx_scatter<<<dim3(20, B_N), dim3(256), 0, stream>>>(tokens, alignW, mask, ca, wstart,
                                                           out_ctx, out_align, out_cum);
}

// Round 6
// 361.817 us; speedup vs baseline: 1.1582x; 1.0080x over previous
//
#include <hip/hip_runtime.h>
#include <math.h>

#define T_LEN 4096
#define B_N 64
#define H_N 256
#define Q_N 1024
#define K_F 31
#define PAD 15
#define WL 1024

__device__ __forceinline__ float tanh_fast(float x) {
    // tanh(x) = 1 - 2/(exp(2x)+1); exact at +-inf saturation
    float e = __expf(2.0f * x);
    return 1.0f - 2.0f / (e + 1.0f);
}

// ---------------- K1: fused query-GEMV + conv + tanh + partial score
// grid (8, B): block handles h-chunk hc (32 h) for batch b, all 1024 w.
// Also prefetches its 128-row slice of the token window (128 KB) through
// L2/L3 during the VALU-bound conv loop, so k_fused's context hits L3.
// hc==0 block zeroes out_ctx[b] (ordered before k_fused by kernel boundary).
__global__ __launch_bounds__(256) void k_score(
        const float* __restrict__ tokens,
        const float* __restrict__ query, const float* __restrict__ wq,
        const float* __restrict__ bq, const float* __restrict__ conv_b,
        const float* __restrict__ ca, const int* __restrict__ mask,
        const float* __restrict__ init, const int* __restrict__ wstart,
        const float* __restrict__ conv_w, const float* __restrict__ ws_vec,
        float* __restrict__ scoreP, float* __restrict__ out_ctx) {
    int hc = blockIdx.x, b = blockIdx.y, tid = threadIdx.x;
    int h0 = hc * 32;
    __shared__ __align__(16) float qbuf[Q_N];
    __shared__ __align__(16) float loc[1056];
    __shared__ __align__(16) float cw[32][32];   // padded cols 31.. = 0
    __shared__ float qv[32], wv[32];
    int wsb = wstart[b];

    if (hc == 0) out_ctx[b * H_N + tid] = 0.f;   // 256 threads == H_N

    for (int i = tid; i < Q_N; i += 256) qbuf[i] = query[b * Q_N + i];
    for (int i = tid; i < 1056; i += 256) {
        float v = 0.f;
        if (i < 1054) {
            int p = wsb + i;
            if (p < PAD) v = init[b];
            else {
                int t = p - PAD;
                if (t < T_LEN && mask[b * T_LEN + t] != 0) v = ca[b * T_LEN + t];
            }
        }
        loc[i] = v;
    }
    for (int i = tid; i < 32 * 32; i += 256) {
        int r = i >> 5, c = i & 31;
        cw[r][c] = (c < K_F) ? conv_w[(h0 + r) * K_F + c] : 0.f;
    }
    if (tid < 32) wv[tid] = ws_vec[h0 + tid];
    __syncthreads();

    // q[h] = dot(query[b,:], wq[h0+h,:]) + bq + conv_b ; 8 threads per h-row
    {
        int h = tid >> 3, part = tid & 7;
        const float4* wrow = (const float4*)(wq + (size_t)(h0 + h) * Q_N) + part * 32;
        const float4* qrow = (const float4*)qbuf + part * 32;
        float acc = 0.f;
        #pragma unroll 8
        for (int i = 0; i < 32; i++) {
            float4 a = wrow[i], c = qrow[i];
            acc += a.x * c.x + a.y * c.y + a.z * c.z + a.w * c.w;
        }
        acc += __shfl_xor(acc, 1);
        acc += __shfl_xor(acc, 2);
        acc += __shfl_xor(acc, 4);
        if (part == 0) qv[h] = acc + bq[h0 + h] + conv_b[h0 + h];
    }
    __syncthreads();

    int w0 = tid * 4;                 // 4 consecutive w per thread
    // vectorized LDS read: 9 x float4 instead of 35 stride-4 scalar reads
    float4 lv4[9];
    #pragma unroll
    for (int j = 0; j < 9; j++) lv4[j] = *(const float4*)&loc[w0 + 4 * j];
    const float* l = (const float*)lv4;

    // token-window prefetch setup: this block's slice = w rows
    // [wsb + hc*128, +128), all 256 h -> 8192 float4, 32 per thread.
    // 4-deep pipeline: consume the load issued 4 hh-iterations ago
    // (~1080 cyc of conv FMAs > ~900 cyc HBM latency -> no stall).
    const float4* tok4 = (const float4*)(tokens + ((size_t)(wsb + hc * 128) * B_N + b) * H_N);
    float4 pf[4];
    #pragma unroll
    for (int u = 0; u < 4; u++) {
        int idx = u * 256 + tid;
        pf[u] = tok4[(size_t)(idx >> 6) * (B_N * H_N / 4) + (idx & 63)];
    }

    float s0 = 0.f, s1 = 0.f, s2 = 0.f, s3 = 0.f;
    for (int hg = 0; hg < 8; hg++) {
        #pragma unroll
        for (int u = 0; u < 4; u++) {
            int hh = hg * 4 + u;
            float bias = qv[hh];
            float c0 = bias, c1 = bias, c2 = bias, c3 = bias;
            #pragma unroll
            for (int k = 0; k < 32; k += 4) {
                float4 cq = *(const float4*)&cw[hh][k];
                c0 += l[k + 0] * cq.x; c1 += l[k + 1] * cq.x; c2 += l[k + 2] * cq.x; c3 += l[k + 3] * cq.x;
                c0 += l[k + 1] * cq.y; c1 += l[k + 2] * cq.y; c2 += l[k + 3] * cq.y; c3 += l[k + 4] * cq.y;
                c0 += l[k + 2] * cq.z; c1 += l[k + 3] * cq.z; c2 += l[k + 4] * cq.z; c3 += l[k + 5] * cq.z;
                c0 += l[k + 3] * cq.w; c1 += l[k + 4] * cq.w; c2 += l[k + 5] * cq.w; c3 += l[k + 6] * cq.w;
            }
            float wh = wv[hh];
            s0 += wh * tanh_fast(c0); s1 += wh * tanh_fast(c1);
            s2 += wh * tanh_fast(c2); s3 += wh * tanh_fast(c3);
            // consume prefetch issued 4 iterations ago (keeps load live, no DCE),
            // then reissue this slot for hh+4. u is compile-time -> static index.
            asm volatile("" :: "v"(pf[u].x), "v"(pf[u].y), "v"(pf[u].z), "v"(pf[u].w));
            if (hg < 7) {
                int idx = (hh + 4) * 256 + tid;
                pf[u] = tok4[(size_t)(idx >> 6) * (B_N * H_N / 4) + (idx & 63)];
            }
        }
    }
    *(float4*)&scoreP[((size_t)hc * B_N + b) * WL + w0] = make_float4(s0, s1, s2, s3);
}

// ---------------- K2 (fused): redundant per-block softmax from scoreP, then
// context (bx<16), T-scatter (bx>=16), argmax+nws (bx==0).
// Softmax is deterministic -> all 20 blocks of a b get identical alignments.
// grid (20, B), 256 threads.
__global__ __launch_bounds__(256) void k_fused(
        const float* __restrict__ scoreP, const int* __restrict__ mask,
        const int* __restrict__ wstart, const int* __restrict__ num_tokens,
        const float* __restrict__ tokens, const float* __restrict__ ca,
        float* __restrict__ out_ctx, float* __restrict__ out_align,
        float* __restrict__ out_cum, float* __restrict__ out_nws) {
    int bx = blockIdx.x, b = blockIdx.y, tid = threadIdx.x;
    int wsb = wstart[b];
    __shared__ float sc[WL];
    __shared__ float red[8];    // [0..3] max, [4..7] sum
    __shared__ float redv[4];
    __shared__ int redi[4];
    __shared__ __align__(16) float4 red4[256];

    // ---- softmax over the 8 scoreP planes (identical math to old k_softmax) ----
    float s[4];
    #pragma unroll
    for (int k = 0; k < 4; k++) {
        int w = tid + 256 * k;
        float v = 0.f;
        #pragma unroll
        for (int p = 0; p < 8; p++) v += scoreP[((size_t)p * B_N + b) * WL + w];
        if (mask[b * T_LEN + wsb + w] == 0) v = -3.0e38f;
        s[k] = v;
    }
    float mx = fmaxf(fmaxf(s[0], s[1]), fmaxf(s[2], s[3]));
    #pragma unroll
    for (int o = 32; o > 0; o >>= 1) mx = fmaxf(mx, __shfl_xor(mx, o));
    if ((tid & 63) == 0) red[tid >> 6] = mx;
    __syncthreads();
    mx = fmaxf(fmaxf(red[0], red[1]), fmaxf(red[2], red[3]));

    float lsum = 0.f;
    #pragma unroll
    for (int k = 0; k < 4; k++) { s[k] = __expf(s[k] - mx); lsum += s[k]; }
    #pragma unroll
    for (int o = 32; o > 0; o >>= 1) lsum += __shfl_xor(lsum, o);
    if ((tid & 63) == 0) red[4 + (tid >> 6)] = lsum;
    __syncthreads();
    float inv = 1.0f / (red[4] + red[5] + red[6] + red[7]);

    float bv = -1.f; int bi = 0;
    #pragma unroll
    for (int k = 0; k < 4; k++) {       // ascending w within thread: strict > keeps first tie
        float a = s[k] * inv;
        sc[tid + 256 * k] = a;
        if (a > bv) { bv = a; bi = tid + 256 * k; }
    }
    __syncthreads();                    // sc[] visible to all threads

    if (bx < 16) {
        // ---- context: 64-w chunk bx, h-quad (tid&63)*4, w-subgroup tid>>6 ----
        int h4 = (tid & 63) * 4, wj = tid >> 6;
        const float* avs = &sc[bx * 64];
        const float* tokbase = tokens + ((size_t)(wsb + bx * 64 + wj) * B_N + b) * H_N + h4;
        float4 acc = make_float4(0.f, 0.f, 0.f, 0.f);
        #pragma unroll
        for (int j = 0; j < 16; j++) {      // fully unrolled: 16 independent loads in flight
            float a = avs[wj + 4 * j];
            float4 t4 = *(const float4*)(tokbase + (size_t)(4 * j) * B_N * H_N);
            acc.x += a * t4.x; acc.y += a * t4.y; acc.z += a * t4.z; acc.w += a * t4.w;
        }
        red4[tid] = acc;
        if (bx == 0) {
            // ---- argmax + nws (same tie-break sequence as before) ----
            #pragma unroll
            for (int o = 32; o > 0; o >>= 1) {
                float ov = __shfl_xor(bv, o); int oi = __shfl_xor(bi, o);
                if (ov > bv || (ov == bv && oi < bi)) { bv = ov; bi = oi; }
            }
            if ((tid & 63) == 0) { redv[tid >> 6] = bv; redi[tid >> 6] = bi; }
        }
        __syncthreads();
        if (tid < 64) {
            float4 r0 = red4[tid], r1 = red4[tid + 64], r2 = red4[tid + 128], r3 = red4[tid + 192];
            float* dst = &out_ctx[b * H_N + tid * 4];
            atomicAdd(dst + 0, r0.x + r1.x + r2.x + r3.x);
            atomicAdd(dst + 1, r0.y + r1.y + r2.y + r3.y);
            atomicAdd(dst + 2, r0.z + r1.z + r2.z + r3.z);
            atomicAdd(dst + 3, r0.w + r1.w + r2.w + r3.w);
        }
        if (bx == 0 && tid == 0) {
            float v = redv[0]; int i = redi[0];
            #pragma unroll
            for (int k = 1; k < 4; k++)
                if (redv[k] > v || (redv[k] == v && redi[k] < i)) { v = redv[k]; i = redi[k]; }
            int tstar = wsb + i;
            int nws = tstar - WL / 2;
            int lim = num_tokens[b] - WL;
            nws = nws < lim ? nws : lim;
            nws = nws > 0 ? nws : 0;
            out_nws[b] = (float)nws;
        }
    } else {
        // ---- T-scatter: 4 blocks per b, one float4 group of T per thread ----
        int t4 = (bx - 16) * 256 + tid;     // float4 group index in [0, T/4)
        int4 m4 = ((const int4*)(mask + (size_t)b * T_LEN))[t4];
        float4 c4 = ((const float4*)(ca + (size_t)b * T_LEN))[t4];
        int j0 = t4 * 4 - wsb;
        float4 av4;
        av4.x = ((unsigned)(j0 + 0) < WL) ? sc[j0 + 0] : 0.f;
        av4.y = ((unsigned)(j0 + 1) < WL) ? sc[j0 + 1] : 0.f;
        av4.z = ((unsigned)(j0 + 2) < WL) ? sc[j0 + 2] : 0.f;
        av4.w = ((unsigned)(j0 + 3) < WL) ? sc[j0 + 3] : 0.f;
        float4 cum;
        cum.x = (m4.x != 0 ? c4.x : 0.f) + av4.x;
        cum.y = (m4.y != 0 ? c4.y : 0.f) + av4.y;
        cum.z = (m4.z != 0 ? c4.z : 0.f) + av4.z;
        cum.w = (m4.w != 0 ? c4.w : 0.f) + av4.w;
        ((float4*)(out_align + (size_t)b * T_LEN))[t4] = av4;
        ((float4*)(out_cum + (size_t)b * T_LEN))[t4] = cum;
    }
}

extern "C" void kernel_launch(void* const* d_in, const int* in_sizes, int n_in,
                              void* d_out, int out_size, void* d_ws, size_t ws_size,
                              hipStream_t stream) {
    const float* tokens     = (const float*)d_in[0];
    const int*   mask       = (const int*)  d_in[1];
    const int*   num_tokens = (const int*)  d_in[2];
    const float* query      = (const float*)d_in[3];   // (1,B,Q) -> base is query[0]
    const float* ca         = (const float*)d_in[4];
    const float* init       = (const float*)d_in[5];
    const int*   wstart     = (const int*)  d_in[6];
    const float* conv_w     = (const float*)d_in[7];
    const float* conv_b     = (const float*)d_in[8];
    const float* wq         = (const float*)d_in[9];
    const float* bq         = (const float*)d_in[10];
    const float* ws_vec     = (const float*)d_in[11];

    float* out       = (float*)d_out;
    float* out_ctx   = out;                          // B*H   = 16384
    float* out_cum   = out + 16384;                  // B*T   = 262144
    float* out_align = out + 16384 + 262144;         // B*T   = 262144
    float* out_nws   = out + 16384 + 2 * 262144;     // B     = 64 (as float)

    float* scoreP = (float*)d_ws;                    // 8*B*WL floats = 2MB

    k_score<<<dim3(8, B_N),  dim3(256), 0, stream>>>(tokens, query, wq, bq, conv_b, ca, mask,
                                                     init, wstart, conv_w, ws_vec, scoreP, out_ctx);
    k_fused<<<dim3(20, B_N), dim3(256), 0, stream>>>(scoreP, mask, wstart, num_tokens, tokens, ca,
                                                     out_ctx, out_align, out_cum, out_nws);
}